// Round 8
// baseline (539.248 us; speedup 1.0000x reference)
//
#include <hip/hip_runtime.h>
#include <hip/hip_fp16.h>
#include <math.h>

#define N_NODES 50000
#define N_EDGES 1600000
#define N_GRAPHS 512
#define F_IN 9
#define H 64
#define SCAN_BLOCK 1024
#define N_CHUNKS ((N_NODES + SCAN_BLOCK - 1) / SCAN_BLOCK)   // 49

// ---------- prep: block 0 transposes weights, blocks >=1 histogram dst ----------
__global__ void prep_kernel(const int* __restrict__ ei, int* __restrict__ deg,
                            const float* __restrict__ w1a,
                            const float* __restrict__ w1b,
                            const float* __restrict__ w2a,
                            const float* __restrict__ w2b,
                            const float* __restrict__ wr1,
                            float* __restrict__ w1aT,
                            float* __restrict__ w1bT,
                            float* __restrict__ w2aT,
                            float* __restrict__ w2bT,
                            float* __restrict__ wr1T) {
    if (blockIdx.x == 0) {
        int t = threadIdx.x;
        for (int i = t; i < H * F_IN; i += 256) {
            int f = i / F_IN, k = i % F_IN;
            w1aT[k * H + f] = w1a[i];
        }
        for (int i = t; i < H * H; i += 256) {
            int f = i / H, k = i % H;
            w1bT[k * H + f] = w1b[i];
            w2aT[k * H + f] = w2a[i];
            w2bT[k * H + f] = w2b[i];
        }
        for (int i = t; i < 32 * H; i += 256) {
            int f = i / H, k = i % H;
            wr1T[k * 32 + f] = wr1[i];
        }
        return;
    }
    int t = (blockIdx.x - 1) * blockDim.x + threadIdx.x;
    if (t >= N_EDGES / 4) return;
    int4 d4 = ((const int4*)(ei + N_EDGES))[t];
    atomicAdd(&deg[d4.x], 1);
    atomicAdd(&deg[d4.y], 1);
    atomicAdd(&deg[d4.z], 1);
    atomicAdd(&deg[d4.w], 1);
}

__global__ void scan_local(const int* __restrict__ deg,
                           int* __restrict__ starts,
                           int* __restrict__ csum) {
    __shared__ int wsum[16];
    __shared__ int woff[16];
    int tid = threadIdx.x, lane = tid & 63, wid = tid >> 6;
    int i = blockIdx.x * SCAN_BLOCK + tid;
    int v = (i < N_NODES) ? deg[i] : 0;
    int incl = v;
#pragma unroll
    for (int off = 1; off < 64; off <<= 1) {
        int t = __shfl_up(incl, off, 64);
        if (lane >= off) incl += t;
    }
    if (lane == 63) wsum[wid] = incl;
    __syncthreads();
    if (wid == 0) {
        int wv = (lane < 16) ? wsum[lane] : 0;
        int winc = wv;
#pragma unroll
        for (int off = 1; off < 16; off <<= 1) {
            int t = __shfl_up(winc, off, 64);
            if (lane >= off) winc += t;
        }
        if (lane < 16) woff[lane] = winc - wv;
    }
    __syncthreads();
    if (i < N_NODES) starts[i] = woff[wid] + (incl - v);
    if (tid == 0) csum[blockIdx.x] = woff[15] + wsum[15];
}

__global__ void scan_top(const int* __restrict__ csum, int* __restrict__ coff) {
    int lane = threadIdx.x;
    int v = (lane < N_CHUNKS) ? csum[lane] : 0;
    int incl = v;
#pragma unroll
    for (int off = 1; off < 64; off <<= 1) {
        int t = __shfl_up(incl, off, 64);
        if (lane >= off) incl += t;
    }
    if (lane < N_CHUNKS) coff[lane] = incl - v;
}

__global__ void scan_add(int* __restrict__ starts, int* __restrict__ next,
                         const int* __restrict__ coff) {
    int i = blockIdx.x * SCAN_BLOCK + threadIdx.x;
    if (i >= N_NODES) return;
    int s = starts[i] + coff[blockIdx.x];
    starts[i] = s;
    next[i] = s;
}

__global__ void scatter_kernel(const int* __restrict__ ei,
                               const float* __restrict__ ea,
                               int* __restrict__ next,
                               int2* __restrict__ epay) {
    int e = blockIdx.x * blockDim.x + threadIdx.x;
    if (e >= N_EDGES) return;
    int d = ei[N_EDGES + e];
    int pos = atomicAdd(&next[d], 1);
    epay[pos] = make_int2(ei[e], __float_as_int(ea[e]));
}

// ---------- conv1 fused: aggregation (4 slots x 16 lanes, unroll 4) + MLP;
// h1 written as two feature-split halves (32 feats each, 64B rows) ----------
__global__ void conv1_kernel(const float* __restrict__ x,
                             const int* __restrict__ starts,
                             const int* __restrict__ deg,
                             const int2* __restrict__ epay,
                             const float* __restrict__ e1w,
                             const float* __restrict__ e1b,
                             const float* __restrict__ w1aT,
                             const float* __restrict__ b1a,
                             const float* __restrict__ w1bT,
                             const float* __restrict__ b1b,
                             __half* __restrict__ h1lo,
                             __half* __restrict__ h1hi) {
    int n = blockIdx.x * (blockDim.x >> 6) + (threadIdx.x >> 6);
    int lane = threadIdx.x & 63;
    if (n >= N_NODES) return;
    int slot = lane >> 4;
    int f = lane & 15;
    int s0 = starts[n], dg = deg[n];
    bool act = f < F_IN;
    float wf = act ? e1w[f] : 0.f;
    float bf = act ? e1b[f] : 0.f;
    float acc = 0.f;
    int j = slot;
    for (; j + 12 < dg; j += 16) {
        int2 pa = epay[s0 + j];
        int2 pb = epay[s0 + j + 4];
        int2 pc = epay[s0 + j + 8];
        int2 pd = epay[s0 + j + 12];
        float xa_ = act ? x[pa.x * F_IN + f] : 0.f;
        float xb_ = act ? x[pb.x * F_IN + f] : 0.f;
        float xc_ = act ? x[pc.x * F_IN + f] : 0.f;
        float xd_ = act ? x[pd.x * F_IN + f] : 0.f;
        if (act) {
            acc += fmaxf(xa_ + __int_as_float(pa.y) * wf + bf, 0.f)
                 + fmaxf(xb_ + __int_as_float(pb.y) * wf + bf, 0.f)
                 + fmaxf(xc_ + __int_as_float(pc.y) * wf + bf, 0.f)
                 + fmaxf(xd_ + __int_as_float(pd.y) * wf + bf, 0.f);
        }
    }
    for (; j < dg; j += 4) {
        int2 p = epay[s0 + j];
        float xv = act ? x[p.x * F_IN + f] : 0.f;
        float m = xv + __int_as_float(p.y) * wf + bf;
        acc += act ? fmaxf(m, 0.f) : 0.f;
    }
    acc += __shfl_xor(acc, 16, 64);
    acc += __shfl_xor(acc, 32, 64);
    float xa = (lane < F_IN) ? x[n * F_IN + lane] + acc : 0.f;
    float a1 = b1a[lane];
#pragma unroll
    for (int k = 0; k < F_IN; ++k)
        a1 += __shfl(xa, k, 64) * w1aT[k * H + lane];
    float ha = fmaxf(a1, 0.f);
    float a2 = b1b[lane];
#pragma unroll 16
    for (int k = 0; k < H; ++k)
        a2 += __shfl(ha, k, 64) * w1bT[k * H + lane];
    __half hv = __float2half(fmaxf(a2, 0.f));
    if (lane < 32) h1lo[n * 32 + lane] = hv;
    else           h1hi[n * 32 + (lane - 32)] = hv;
}

// one aggregation phase over a 3.2MB half-array (L2-resident per XCD).
// lane = half*32 + fh: half = edge parity, fh = feature within the 32-block.
__device__ __forceinline__ float agg_phase(const __half* __restrict__ harr,
                                           const int2* __restrict__ ep,
                                           int dg, int half, int fh,
                                           float wf, float bf) {
    float acc = 0.f;
    int j = 0;
    for (; j + 16 <= dg; j += 16) {   // 8 gathers in flight = 16 edges
        int2 p0 = ep[j +  0 + half], p1 = ep[j +  2 + half];
        int2 p2 = ep[j +  4 + half], p3 = ep[j +  6 + half];
        int2 p4 = ep[j +  8 + half], p5 = ep[j + 10 + half];
        int2 p6 = ep[j + 12 + half], p7 = ep[j + 14 + half];
        float v0 = __half2float(harr[p0.x * 32 + fh]);
        float v1 = __half2float(harr[p1.x * 32 + fh]);
        float v2 = __half2float(harr[p2.x * 32 + fh]);
        float v3 = __half2float(harr[p3.x * 32 + fh]);
        float v4 = __half2float(harr[p4.x * 32 + fh]);
        float v5 = __half2float(harr[p5.x * 32 + fh]);
        float v6 = __half2float(harr[p6.x * 32 + fh]);
        float v7 = __half2float(harr[p7.x * 32 + fh]);
        acc += fmaxf(v0 + __int_as_float(p0.y) * wf + bf, 0.f)
             + fmaxf(v1 + __int_as_float(p1.y) * wf + bf, 0.f)
             + fmaxf(v2 + __int_as_float(p2.y) * wf + bf, 0.f)
             + fmaxf(v3 + __int_as_float(p3.y) * wf + bf, 0.f)
             + fmaxf(v4 + __int_as_float(p4.y) * wf + bf, 0.f)
             + fmaxf(v5 + __int_as_float(p5.y) * wf + bf, 0.f)
             + fmaxf(v6 + __int_as_float(p6.y) * wf + bf, 0.f)
             + fmaxf(v7 + __int_as_float(p7.y) * wf + bf, 0.f);
    }
    for (; j + 2 <= dg; j += 2) {
        int2 p = ep[j + half];
        acc += fmaxf(__half2float(harr[p.x * 32 + fh]) + __int_as_float(p.y) * wf + bf, 0.f);
    }
    if (j < dg && half == 0) {
        int2 p = ep[j];
        acc += fmaxf(__half2float(harr[p.x * 32 + fh]) + __int_as_float(p.y) * wf + bf, 0.f);
    }
    // combine edge-parity halves: every lane now holds the sum for feature fh
    acc += __shfl_xor(acc, 32, 64);
    return acc;
}

// ---------- conv2: two-phase L2-resident gather + MLP + readout ----------
__global__ void agg2_node2_kernel(const __half* __restrict__ h1lo,
                                  const __half* __restrict__ h1hi,
                                  const int* __restrict__ starts,
                                  const int* __restrict__ deg,
                                  const int2* __restrict__ epay,
                                  const float* __restrict__ e2w,
                                  const float* __restrict__ e2b,
                                  const float* __restrict__ w2aT,
                                  const float* __restrict__ b2a,
                                  const float* __restrict__ w2bT,
                                  const float* __restrict__ b2b,
                                  const float* __restrict__ wr1T,
                                  const float* __restrict__ br1,
                                  const float* __restrict__ wr2,
                                  const float* __restrict__ br2,
                                  const int* __restrict__ term,
                                  const float* __restrict__ ccost,
                                  const int* __restrict__ batch,
                                  float* __restrict__ pi,
                                  float* __restrict__ te) {
    int n = blockIdx.x * (blockDim.x >> 6) + (threadIdx.x >> 6);
    int f = threadIdx.x & 63;
    if (n >= N_NODES) return;
    int half = f >> 5;
    int fh = f & 31;
    int s0 = starts[n], dg = deg[n];
    const int2* ep = epay + s0;
    // phase A: features 0..31 ; phase B: features 32..63
    float accA = agg_phase(h1lo, ep, dg, half, fh, e2w[fh], e2b[fh]);
    float accB = agg_phase(h1hi, ep, dg, half, fh, e2w[32 + fh], e2b[32 + fh]);
    // lane f's feature: f<32 -> accA (fh==f), f>=32 -> accB (fh==f-32)
    float aggf = (f < 32) ? accA : accB;
    const __half* hp = (f < 32) ? h1lo : h1hi;
    float h = __half2float(hp[n * 32 + fh]) + aggf;
    float m1 = b2a[f];
#pragma unroll 16
    for (int k = 0; k < H; ++k)
        m1 += __shfl(h, k, 64) * w2aT[k * H + f];
    float h2a = fmaxf(m1, 0.f);
    float m2 = b2b[f];
#pragma unroll 16
    for (int k = 0; k < H; ++k)
        m2 += __shfl(h2a, k, 64) * w2bT[k * H + f];
    float h2 = fmaxf(m2, 0.f);
    int fr = f & 31;
    float accr = br1[fr];
#pragma unroll 16
    for (int k = 0; k < H; ++k)
        accr += __shfl(h2, k, 64) * wr1T[k * 32 + fr];
    float r = fmaxf(accr, 0.f);
    float val = (f < 32) ? r * wr2[fr] : 0.f;
#pragma unroll
    for (int off = 32; off > 0; off >>= 1)
        val += __shfl_xor(val, off, 64);
    if (f == 0) {
        float z = val + br2[0];
        float sig = 1.f / (1.f + expf(-z));
        float p = sig * (1.f - (float)term[n]);
        pi[n] = p;
        atomicAdd(&te[batch[n]], p * ccost[n]);
    }
}

__global__ void final_kernel(const float* __restrict__ pi,
                             const int* __restrict__ batch,
                             const float* __restrict__ Btot,
                             const float* __restrict__ te,
                             float* __restrict__ out) {
    int n = blockIdx.x * blockDim.x + threadIdx.x;
    if (n >= N_NODES) return;
    int b = batch[n];
    float ratio = fminf(Btot[b] / (te[b] + 1e-12f), 1.f);
    out[n] = pi[n] * ratio;
}

extern "C" void kernel_launch(void* const* d_in, const int* in_sizes, int n_in,
                              void* d_out, int out_size, void* d_ws, size_t ws_size,
                              hipStream_t stream) {
    const float* x     = (const float*)d_in[0];
    const int*   ei    = (const int*)d_in[1];
    const float* ea    = (const float*)d_in[2];
    const int*   batch = (const int*)d_in[3];
    const float* Btot  = (const float*)d_in[4];
    const int*   term  = (const int*)d_in[5];
    const float* ccost = (const float*)d_in[6];
    const float* e1w   = (const float*)d_in[7];
    const float* e1b   = (const float*)d_in[8];
    const float* w1a   = (const float*)d_in[9];
    const float* b1a   = (const float*)d_in[10];
    const float* w1b   = (const float*)d_in[11];
    const float* b1b   = (const float*)d_in[12];
    const float* e2w   = (const float*)d_in[13];
    const float* e2b   = (const float*)d_in[14];
    const float* w2a   = (const float*)d_in[15];
    const float* b2a   = (const float*)d_in[16];
    const float* w2b   = (const float*)d_in[17];
    const float* b2b   = (const float*)d_in[18];
    const float* wr1   = (const float*)d_in[19];
    const float* br1   = (const float*)d_in[20];
    const float* wr2   = (const float*)d_in[21];
    const float* br2   = (const float*)d_in[22];

    char* p = (char*)d_ws;
    int*    deg    = (int*)p;    p += sizeof(int)    * N_NODES;   // zeroed
    float*  te     = (float*)p;  p += sizeof(float)  * N_GRAPHS;  // zeroed
    int*    starts = (int*)p;    p += sizeof(int)    * N_NODES;
    int*    next   = (int*)p;    p += sizeof(int)    * N_NODES;
    int*    csum   = (int*)p;    p += sizeof(int)    * 64;
    int*    coff   = (int*)p;    p += sizeof(int)    * 64;
    int2*   epay   = (int2*)p;   p += sizeof(int2)   * (size_t)N_EDGES;
    __half* h1lo   = (__half*)p; p += sizeof(__half) * (size_t)N_NODES * 32;
    __half* h1hi   = (__half*)p; p += sizeof(__half) * (size_t)N_NODES * 32;
    float*  pi     = (float*)p;  p += sizeof(float)  * N_NODES;
    float*  w1aT   = (float*)p;  p += sizeof(float)  * F_IN * H;
    float*  w1bT   = (float*)p;  p += sizeof(float)  * H * H;
    float*  w2aT   = (float*)p;  p += sizeof(float)  * H * H;
    float*  w2bT   = (float*)p;  p += sizeof(float)  * H * H;
    float*  wr1T   = (float*)p;  p += sizeof(float)  * H * 32;
    float*  out    = (float*)d_out;

    hipMemsetAsync(d_ws, 0, sizeof(int) * N_NODES + sizeof(float) * N_GRAPHS, stream);

    prep_kernel<<<1 + (N_EDGES / 4 + 255) / 256, 256, 0, stream>>>(
        ei, deg, w1a, w1b, w2a, w2b, wr1, w1aT, w1bT, w2aT, w2bT, wr1T);
    scan_local<<<N_CHUNKS, SCAN_BLOCK, 0, stream>>>(deg, starts, csum);
    scan_top<<<1, 64, 0, stream>>>(csum, coff);
    scan_add<<<N_CHUNKS, SCAN_BLOCK, 0, stream>>>(starts, next, coff);
    scatter_kernel<<<(N_EDGES + 255) / 256, 256, 0, stream>>>(ei, ea, next, epay);
    conv1_kernel<<<(N_NODES + 3) / 4, 256, 0, stream>>>(x, starts, deg, epay,
                                                        e1w, e1b, w1aT, b1a, w1bT, b1b,
                                                        h1lo, h1hi);
    agg2_node2_kernel<<<(N_NODES + 3) / 4, 256, 0, stream>>>(h1lo, h1hi, starts, deg, epay,
                                                             e2w, e2b, w2aT, b2a, w2bT, b2b,
                                                             wr1T, br1, wr2, br2,
                                                             term, ccost, batch, pi, te);
    final_kernel<<<(N_NODES + 255) / 256, 256, 0, stream>>>(pi, batch, Btot, te, out);
}